// Round 13
// baseline (386.230 us; speedup 1.0000x reference)
//
#include <hip/hip_runtime.h>
#include <hip/hip_bf16.h>

#define HW 9216   // 96*96
#define CIN 128
#define COUT 128

typedef _Float16 half8 __attribute__((ext_vector_type(8)));
typedef float f32x4 __attribute__((ext_vector_type(4)));

__device__ __forceinline__ float fast_exp2(float x) {
    float r;
    asm("v_exp_f32 %0, %1" : "=v"(r) : "v"(x));
    return r;
}

__device__ __forceinline__ void mfma16(f32x4& d, half8 a, half8 b) {
    asm("v_mfma_f32_16x16x32_f16 %0, %1, %2, %0" : "+v"(d) : "v"(a), "v"(b));
}

__device__ __forceinline__ void gl_lds16(const void* g, void* l) {
    __builtin_amdgcn_global_load_lds(
        (const __attribute__((address_space(1))) unsigned int*)g,
        (__attribute__((address_space(3))) unsigned int*)l, 16, 0, 0);
}

__device__ __forceinline__ unsigned short h_bits(_Float16 h) {
    return __builtin_bit_cast(unsigned short, h);
}

// ---------------- Kernel 0: prep (unchanged) ----------------
__global__ __launch_bounds__(256) void prep(
    const float* __restrict__ x,
    const float* __restrict__ wq, const float* __restrict__ wk,
    _Float16* __restrict__ xh_t, _Float16* __restrict__ xl_t,
    _Float16* __restrict__ wh_t, _Float16* __restrict__ wl_t)
{
    const int tid = threadIdx.x;
    const int bx = blockIdx.x;
    const int b = blockIdx.y;

    if (bx >= 144) {
        if (b) return;
        int o = (bx - 144) * 32 + (tid >> 3);
        int k0 = (tid & 7) * 16;
        const float* src = (o < 128) ? (wq + o * 128) : (wk + (o - 128) * 128);
        float vals[16];
        #pragma unroll
        for (int t = 0; t < 4; ++t)
            *(float4*)&vals[t * 4] = *(const float4*)&src[k0 + t * 4];
        half8 h0, h1, l0, l1;
        #pragma unroll
        for (int j = 0; j < 8; ++j) {
            _Float16 h = (_Float16)vals[j];
            h0[j] = h; l0[j] = (_Float16)(vals[j] - (float)h);
            _Float16 h2 = (_Float16)vals[j + 8];
            h1[j] = h2; l1[j] = (_Float16)(vals[j + 8] - (float)h2);
        }
        int s = (o & 7) << 3;
        *(half8*)&wh_t[o * 128 + (k0 ^ s)]       = h0;
        *(half8*)&wh_t[o * 128 + ((k0 + 8) ^ s)] = h1;
        *(half8*)&wl_t[o * 128 + (k0 ^ s)]       = l0;
        *(half8*)&wl_t[o * 128 + ((k0 + 8) ^ s)] = l1;
        return;
    }

    __shared__ unsigned int lds[64 * 128];
    const int pixbase = bx * 64;
    const int p = tid & 63;
    const int kw = tid >> 6;
    const float* xb = x + (size_t)b * CIN * HW + pixbase + p;

    #pragma unroll
    for (int i = 0; i < 32; ++i) {
        int k = kw * 32 + i;
        float v = xb[(size_t)k * HW];
        _Float16 h = (_Float16)v;
        _Float16 l = (_Float16)(v - (float)h);
        unsigned int pack = (unsigned int)h_bits(h) | ((unsigned int)h_bits(l) << 16);
        lds[(p * 128 + k) ^ (p & 31)] = pack;
    }
    __syncthreads();

    const int p2 = tid >> 2;
    const int qk = (tid & 3) * 32;
    const int s = (p2 & 7) << 3;
    unsigned int hw_[16], lw_[16];
    #pragma unroll
    for (int i = 0; i < 16; ++i) {
        int pos0 = qk + 2 * i;
        int src0 = pos0 ^ s;
        unsigned int a0 = lds[(p2 * 128 + src0) ^ (p2 & 31)];
        unsigned int a1 = lds[(p2 * 128 + src0 + 1) ^ (p2 & 31)];
        hw_[i] = (a0 & 0xffffu) | (a1 << 16);
        lw_[i] = (a0 >> 16) | (a1 & 0xffff0000u);
    }
    size_t orow = ((size_t)b * HW + pixbase + p2) * 64 + (qk >> 1);
    unsigned int* oh = (unsigned int*)xh_t;
    unsigned int* ol = (unsigned int*)xl_t;
    #pragma unroll
    for (int i = 0; i < 4; ++i) {
        uint4 th = {hw_[i*4], hw_[i*4+1], hw_[i*4+2], hw_[i*4+3]};
        uint4 tl = {lw_[i*4], lw_[i*4+1], lw_[i*4+2], lw_[i*4+3]};
        *(uint4*)&oh[orow + i * 4] = th;
        *(uint4*)&ol[orow + i * 4] = tl;
    }
}

// ---------------- Kernel 1: conv via f16-split MFMA (unchanged) ----------------
__global__ __launch_bounds__(256) void conv_mfma(
    const _Float16* __restrict__ xh_t, const _Float16* __restrict__ xl_t,
    const _Float16* __restrict__ wh_t, const _Float16* __restrict__ wl_t,
    float* __restrict__ qbuf, float* __restrict__ kbuf)
{
    __shared__ _Float16 xsh[128 * 64];
    __shared__ _Float16 xsl[128 * 64];
    __shared__ _Float16 wsh[128 * 64];
    __shared__ _Float16 wsl[128 * 64];

    const int tid = threadIdx.x;
    const int lane = tid & 63;
    const int wave = tid >> 6;
    const int pixbase = blockIdx.x * 128;
    const int b = blockIdx.y;
    const int half = blockIdx.z;
    const int wbase = half * 128;

    const int wrow = (wave & 1) * 64;
    const int wpix = (wave >> 1) * 64;

    f32x4 acc[4][4];
    #pragma unroll
    for (int m = 0; m < 4; ++m)
        #pragma unroll
        for (int n = 0; n < 4; ++n) { acc[m][n][0]=0.f; acc[m][n][1]=0.f; acc[m][n][2]=0.f; acc[m][n][3]=0.f; }

    const size_t xrow = ((size_t)b * HW + pixbase) * 128;

    #pragma unroll
    for (int kc = 0; kc < 2; ++kc) {
        if (kc) __syncthreads();
        #pragma unroll
        for (int i = 0; i < 4; ++i) {
            int sgl = wave * 4 + i;
            int pix = sgl * 8 + (lane >> 3);
            int j = lane & 7;
            const _Float16* gh = xh_t + xrow + (size_t)pix * 128 + kc * 64 + j * 8;
            const _Float16* gl = xl_t + xrow + (size_t)pix * 128 + kc * 64 + j * 8;
            gl_lds16(gh, (void*)(xsh + sgl * 512));
            gl_lds16(gl, (void*)(xsl + sgl * 512));
        }
        #pragma unroll
        for (int i = 0; i < 4; ++i) {
            int sgl = wave * 4 + i;
            int o = sgl * 8 + (lane >> 3);
            int j = lane & 7;
            const _Float16* gh = wh_t + (size_t)(wbase + o) * 128 + kc * 64 + j * 8;
            const _Float16* gl = wl_t + (size_t)(wbase + o) * 128 + kc * 64 + j * 8;
            gl_lds16(gh, (void*)(wsh + sgl * 512));
            gl_lds16(gl, (void*)(wsl + sgl * 512));
        }
        __syncthreads();

        #pragma unroll
        for (int ks = 0; ks < 2; ++ks) {
            const int kb = ks * 32 + (lane >> 4) * 8;
            half8 ah[4], al[4];
            #pragma unroll
            for (int m = 0; m < 4; ++m) {
                int o = wrow + m * 16 + (lane & 15);
                int idx = (o * 64 + kb) ^ ((o & 7) << 3);
                ah[m] = *(const half8*)&wsh[idx];
                al[m] = *(const half8*)&wsl[idx];
            }
            #pragma unroll
            for (int n = 0; n < 4; ++n) {
                int p = wpix + n * 16 + (lane & 15);
                int idx = (p * 64 + kb) ^ ((p & 7) << 3);
                half8 bh = *(const half8*)&xsh[idx];
                half8 bl = *(const half8*)&xsl[idx];
                #pragma unroll
                for (int m = 0; m < 4; ++m) {
                    mfma16(acc[m][n], ah[m], bh);
                    mfma16(acc[m][n], al[m], bh);
                    mfma16(acc[m][n], ah[m], bl);
                }
            }
        }
    }

    asm volatile("s_nop 7\n\ts_nop 7"
        : "+v"(acc[0][0]), "+v"(acc[0][1]), "+v"(acc[0][2]), "+v"(acc[0][3]),
          "+v"(acc[1][0]), "+v"(acc[1][1]), "+v"(acc[1][2]), "+v"(acc[1][3]),
          "+v"(acc[2][0]), "+v"(acc[2][1]), "+v"(acc[2][2]), "+v"(acc[2][3]),
          "+v"(acc[3][0]), "+v"(acc[3][1]), "+v"(acc[3][2]), "+v"(acc[3][3]));

    float* obuf = half ? kbuf : qbuf;
    #pragma unroll
    for (int m = 0; m < 4; ++m) {
        #pragma unroll
        for (int n = 0; n < 4; ++n) {
            int pc = pixbase + wpix + n * 16 + (lane & 15);
            #pragma unroll
            for (int r = 0; r < 4; ++r) {
                int row = wrow + m * 16 + (lane >> 4) * 4 + r;
                obuf[((size_t)b * COUT + row) * HW + pc] = acc[m][n][r];
            }
        }
    }
}

// ---------------- attn ablation: template<MODE, R> ----------------
// MODE 0: stage halo + barrier only.          (x12 reps)
// MODE 1: + 42 ds_read_b128/thread, math stub. (x8)
// MODE 2: + full math chain, LDS reads hoisted. (x4)
// MODE 3: full v8 body.                        (x4)
// All write per-thread result to scratch (d_ws) -> no DCE, out untouched.
template<int MODE, int R>
__global__ __launch_bounds__(256) void attn_abl(
    const float* __restrict__ qbuf,
    const float* __restrict__ kbuf,
    const float* __restrict__ v,
    const float* __restrict__ rel_h,
    const float* __restrict__ rel_w,
    float* __restrict__ scratch)
{
    __shared__ __align__(16) float ks[38 * 40];
    __shared__ __align__(16) float vs[38 * 40];

    const int tid = threadIdx.x;
    const int tile = blockIdx.x;
    const int bc = blockIdx.y;
    const int c = bc & 127;
    const int tw = (tile % 3) * 32;
    const int th = (tile / 3) * 32;

    const float* kp = kbuf + (size_t)bc * HW;
    const float* vp = v    + (size_t)bc * HW;
    const bool is_h = (c < 64);
    const float* rbase = is_h ? (rel_h + c * 7) : (rel_w + (c - 64) * 7);
    const int ty = tid >> 3;
    const int tx = tid & 7;

    float keep = 0.f;

    #pragma unroll 1
    for (int rep = 0; rep < R; ++rep) {
        // ---- staging (common to all modes) ----
        for (int idx = tid; idx < 38 * 38; idx += 256) {
            int r = idx / 38, cl = idx - r * 38;
            int gr = th - 3 + r, gc = tw - 3 + cl;
            bool ok = ((unsigned)gr < 96u) && ((unsigned)gc < 96u);
            ks[r * 40 + cl] = ok ? kp[gr * 96 + gc] : 0.f;
            vs[r * 40 + cl] = ok ? vp[gr * 96 + gc] : 0.f;
        }

        float r7[7];
        #pragma unroll
        for (int i = 0; i < 7; ++i) r7[i] = rbase[i];

        const float* qrow = qbuf + (size_t)bc * HW + (th + ty) * 96 + tw + tx * 4;
        float4 qa = *(const float4*)qrow;
        const float L2E = 1.4426950408889634f;
        float q2[4] = {qa.x * L2E, qa.y * L2E, qa.z * L2E, qa.w * L2E};

        __syncthreads();

        const float* kb0 = &ks[ty * 40 + tx * 4];
        const float* vb0 = &vs[ty * 40 + tx * 4];

        if constexpr (MODE == 0) {
            keep += ks[tid * 5 & 1023] + vs[tid * 7 & 1023] + q2[0];
        } else if constexpr (MODE == 1) {
            float acc = q2[0];
            #pragma unroll
            for (int dh = 0; dh < 7; ++dh) {
                float kr[12], vr[12];
                #pragma unroll
                for (int t = 0; t < 3; ++t) {
                    *(float4*)&kr[t * 4] = *(const float4*)&kb0[dh * 40 + t * 4];
                    *(float4*)&vr[t * 4] = *(const float4*)&vb0[dh * 40 + t * 4];
                }
                acc += kr[0] + kr[4] + kr[8] + vr[0] + vr[4] + vr[8];
            }
            keep += acc;
        } else if constexpr (MODE == 2) {
            // LDS reads hoisted: one kr/vr set reused; args depend on dh via
            // r7[dh] in BOTH roles so no CSE across dh. Same per-elem chain:
            // mul(hoisted)+fma+exp+add+fma x 4j x 7dw x 7dh = 392 elems.
            float kr[12], vr[12];
            #pragma unroll
            for (int t = 0; t < 3; ++t) {
                *(float4*)&kr[t * 4] = *(const float4*)&kb0[t * 4];
                *(float4*)&vr[t * 4] = *(const float4*)&vb0[t * 4];
            }
            float s[4] = {0.f, 0.f, 0.f, 0.f};
            float a[4] = {0.f, 0.f, 0.f, 0.f};
            #pragma unroll
            for (int dh = 0; dh < 7; ++dh) {
                #pragma unroll
                for (int j = 0; j < 4; ++j) {
                    float qr = q2[j] * r7[dh];
                    #pragma unroll
                    for (int dw = 0; dw < 7; ++dw) {
                        float e = fast_exp2(fmaf(q2[j], kr[j + dw], qr));
                        s[j] += e;
                        a[j] = fmaf(e, vr[j + dw], a[j]);
                    }
                }
            }
            keep += (a[0] + a[1] + a[2] + a[3]) * __builtin_amdgcn_rcpf(s[0] + s[1] + s[2] + s[3] + 1.f);
        } else {
            // full v8 body
            float s[4] = {0.f, 0.f, 0.f, 0.f};
            float a[4] = {0.f, 0.f, 0.f, 0.f};
            #pragma unroll
            for (int dh = 0; dh < 7; ++dh) {
                float kr[12], vr[12];
                #pragma unroll
                for (int t = 0; t < 3; ++t) {
                    *(float4*)&kr[t * 4] = *(const float4*)&kb0[dh * 40 + t * 4];
                    *(float4*)&vr[t * 4] = *(const float4*)&vb0[dh * 40 + t * 4];
                }
                if (is_h) {
                    float rh = r7[dh];
                    #pragma unroll
                    for (int j = 0; j < 4; ++j) {
                        float qr = q2[j] * rh;
                        #pragma unroll
                        for (int dw = 0; dw < 7; ++dw) {
                            float e = fast_exp2(fmaf(q2[j], kr[j + dw], qr));
                            s[j] += e;
                            a[j] = fmaf(e, vr[j + dw], a[j]);
                        }
                    }
                } else {
                    #pragma unroll
                    for (int j = 0; j < 4; ++j) {
                        #pragma unroll
                        for (int dw = 0; dw < 7; ++dw) {
                            float e = fast_exp2(q2[j] * (kr[j + dw] + r7[dw]));
                            s[j] += e;
                            a[j] = fmaf(e, vr[j + dw], a[j]);
                        }
                    }
                }
            }
            keep += a[0] * __builtin_amdgcn_rcpf(s[0]) + a[3] * __builtin_amdgcn_rcpf(s[3]);
        }

        __syncthreads();
        asm volatile("" ::: "memory");
    }

    size_t gtid = ((size_t)blockIdx.y * gridDim.x + blockIdx.x) * 256 + tid;
    scratch[gtid] = keep;
}

// ---------------- Kernel 2: windowed softmax attention v8 (real, unchanged) ----------------
__global__ __launch_bounds__(256) void attn_v8(
    const float* __restrict__ qbuf,
    const float* __restrict__ kbuf,
    const float* __restrict__ v,
    const float* __restrict__ rel_h,
    const float* __restrict__ rel_w,
    float* __restrict__ out)
{
    __shared__ __align__(16) float ks[38 * 40];
    __shared__ __align__(16) float vs[38 * 40];

    const int tid = threadIdx.x;
    const int tile = blockIdx.x;
    const int bc = blockIdx.y;
    const int c = bc & 127;
    const int tw = (tile % 3) * 32;
    const int th = (tile / 3) * 32;

    const float* kp = kbuf + (size_t)bc * HW;
    const float* vp = v    + (size_t)bc * HW;

    for (int idx = tid; idx < 38 * 38; idx += 256) {
        int r = idx / 38, cl = idx - r * 38;
        int gr = th - 3 + r, gc = tw - 3 + cl;
        bool ok = ((unsigned)gr < 96u) && ((unsigned)gc < 96u);
        ks[r * 40 + cl] = ok ? kp[gr * 96 + gc] : 0.f;
        vs[r * 40 + cl] = ok ? vp[gr * 96 + gc] : 0.f;
    }

    const bool is_h = (c < 64);
    const float* rbase = is_h ? (rel_h + c * 7) : (rel_w + (c - 64) * 7);
    float r7[7];
    #pragma unroll
    for (int i = 0; i < 7; ++i) r7[i] = rbase[i];

    const int ty = tid >> 3;
    const int tx = tid & 7;

    const float* qrow = qbuf + (size_t)bc * HW + (th + ty) * 96 + tw + tx * 4;
    float4 qa = *(const float4*)qrow;
    const float L2E = 1.4426950408889634f;
    float q2[4] = {qa.x * L2E, qa.y * L2E, qa.z * L2E, qa.w * L2E};

    float s[4] = {0.f, 0.f, 0.f, 0.f};
    float a[4] = {0.f, 0.f, 0.f, 0.f};

    __syncthreads();

    const float* kb0 = &ks[ty * 40 + tx * 4];
    const float* vb0 = &vs[ty * 40 + tx * 4];

    #pragma unroll
    for (int dh = 0; dh < 7; ++dh) {
        float kr[12], vr[12];
        #pragma unroll
        for (int t = 0; t < 3; ++t) {
            *(float4*)&kr[t * 4] = *(const float4*)&kb0[dh * 40 + t * 4];
            *(float4*)&vr[t * 4] = *(const float4*)&vb0[dh * 40 + t * 4];
        }

        if (is_h) {
            float rh = r7[dh];
            #pragma unroll
            for (int j = 0; j < 4; ++j) {
                float qr = q2[j] * rh;
                #pragma unroll
                for (int dw = 0; dw < 7; ++dw) {
                    float e = fast_exp2(fmaf(q2[j], kr[j + dw], qr));
                    s[j] += e;
                    a[j] = fmaf(e, vr[j + dw], a[j]);
                }
            }
        } else {
            #pragma unroll
            for (int j = 0; j < 4; ++j) {
                #pragma unroll
                for (int dw = 0; dw < 7; ++dw) {
                    float e = fast_exp2(q2[j] * (kr[j + dw] + r7[dw]));
                    s[j] += e;
                    a[j] = fmaf(e, vr[j + dw], a[j]);
                }
            }
        }
    }

    float* orow = out + (size_t)bc * HW + (th + ty) * 96 + tw + tx * 4;
    float4 o4;
    o4.x = a[0] * __builtin_amdgcn_rcpf(s[0]);
    o4.y = a[1] * __builtin_amdgcn_rcpf(s[1]);
    o4.z = a[2] * __builtin_amdgcn_rcpf(s[2]);
    o4.w = a[3] * __builtin_amdgcn_rcpf(s[3]);
    *(float4*)orow = o4;
}

extern "C" void kernel_launch(void* const* d_in, const int* in_sizes, int n_in,
                              void* d_out, int out_size, void* d_ws, size_t ws_size,
                              hipStream_t stream) {
    const float* x  = (const float*)d_in[0];
    const float* v  = (const float*)d_in[1];
    const float* wq = (const float*)d_in[2];
    const float* wk = (const float*)d_in[3];
    const float* rh = (const float*)d_in[4];
    const float* rw = (const float*)d_in[5];
    float* out = (float*)d_out;

    float* qbuf = (float*)d_ws;
    float* kbuf = qbuf + (size_t)2 * COUT * HW;
    _Float16* xh = (_Float16*)(kbuf + (size_t)2 * COUT * HW);
    _Float16* xl = xh + (size_t)2 * HW * 128;
    _Float16* wh = xl + (size_t)2 * HW * 128;
    _Float16* wl = wh + 256 * 128;
    float* scratch = (float*)(wl + 256 * 128);   // 2304*256 floats

    prep<<<dim3(152, 2), 256, 0, stream>>>(x, wq, wk, xh, xl, wh, wl);
    conv_mfma<<<dim3(72, 2, 2), 256, 0, stream>>>(xh, xl, wh, wl, qbuf, kbuf);

    attn_abl<0, 12><<<dim3(9, 256), 256, 0, stream>>>(qbuf, kbuf, v, rh, rw, scratch);
    attn_abl<1, 8><<<dim3(9, 256), 256, 0, stream>>>(qbuf, kbuf, v, rh, rw, scratch);
    attn_abl<2, 4><<<dim3(9, 256), 256, 0, stream>>>(qbuf, kbuf, v, rh, rw, scratch);
    attn_abl<3, 4><<<dim3(9, 256), 256, 0, stream>>>(qbuf, kbuf, v, rh, rw, scratch);

    attn_v8<<<dim3(9, 256), 256, 0, stream>>>(qbuf, kbuf, v, rh, rw, out);
}

// Round 14
// 49.258 us; speedup vs baseline: 7.8409x; 7.8409x over previous
//
#include <hip/hip_runtime.h>
#include <hip/hip_bf16.h>

#define HW 9216   // 96*96
#define CIN 128
#define COUT 128

typedef _Float16 half8 __attribute__((ext_vector_type(8)));
typedef float f32x4 __attribute__((ext_vector_type(4)));
typedef float f32x2 __attribute__((ext_vector_type(2)));

__device__ __forceinline__ float fast_exp2(float x) {
    float r;
    asm("v_exp_f32 %0, %1" : "=v"(r) : "v"(x));
    return r;
}

// Packed f32 ops (gfx90a+/CDNA): 2 lanes of f32 per instruction.
__device__ __forceinline__ f32x2 pk_fma(f32x2 a, f32x2 b, f32x2 c) {
    f32x2 d;
    asm("v_pk_fma_f32 %0, %1, %2, %3" : "=v"(d) : "v"(a), "v"(b), "v"(c));
    return d;
}
__device__ __forceinline__ f32x2 pk_add(f32x2 a, f32x2 b) {
    f32x2 d;
    asm("v_pk_add_f32 %0, %1, %2" : "=v"(d) : "v"(a), "v"(b));
    return d;
}
__device__ __forceinline__ f32x2 pk_mul(f32x2 a, f32x2 b) {
    f32x2 d;
    asm("v_pk_mul_f32 %0, %1, %2" : "=v"(d) : "v"(a), "v"(b));
    return d;
}

__device__ __forceinline__ void mfma16(f32x4& d, half8 a, half8 b) {
    asm("v_mfma_f32_16x16x32_f16 %0, %1, %2, %0" : "+v"(d) : "v"(a), "v"(b));
}

__device__ __forceinline__ void gl_lds16(const void* g, void* l) {
    __builtin_amdgcn_global_load_lds(
        (const __attribute__((address_space(1))) unsigned int*)g,
        (__attribute__((address_space(3))) unsigned int*)l, 16, 0, 0);
}

__device__ __forceinline__ unsigned short h_bits(_Float16 h) {
    return __builtin_bit_cast(unsigned short, h);
}

// ---------------- Kernel 0: prep (unchanged) ----------------
__global__ __launch_bounds__(256) void prep(
    const float* __restrict__ x,
    const float* __restrict__ wq, const float* __restrict__ wk,
    _Float16* __restrict__ xh_t, _Float16* __restrict__ xl_t,
    _Float16* __restrict__ wh_t, _Float16* __restrict__ wl_t)
{
    const int tid = threadIdx.x;
    const int bx = blockIdx.x;
    const int b = blockIdx.y;

    if (bx >= 144) {
        if (b) return;
        int o = (bx - 144) * 32 + (tid >> 3);
        int k0 = (tid & 7) * 16;
        const float* src = (o < 128) ? (wq + o * 128) : (wk + (o - 128) * 128);
        float vals[16];
        #pragma unroll
        for (int t = 0; t < 4; ++t)
            *(float4*)&vals[t * 4] = *(const float4*)&src[k0 + t * 4];
        half8 h0, h1, l0, l1;
        #pragma unroll
        for (int j = 0; j < 8; ++j) {
            _Float16 h = (_Float16)vals[j];
            h0[j] = h; l0[j] = (_Float16)(vals[j] - (float)h);
            _Float16 h2 = (_Float16)vals[j + 8];
            h1[j] = h2; l1[j] = (_Float16)(vals[j + 8] - (float)h2);
        }
        int s = (o & 7) << 3;
        *(half8*)&wh_t[o * 128 + (k0 ^ s)]       = h0;
        *(half8*)&wh_t[o * 128 + ((k0 + 8) ^ s)] = h1;
        *(half8*)&wl_t[o * 128 + (k0 ^ s)]       = l0;
        *(half8*)&wl_t[o * 128 + ((k0 + 8) ^ s)] = l1;
        return;
    }

    __shared__ unsigned int lds[64 * 128];
    const int pixbase = bx * 64;
    const int p = tid & 63;
    const int kw = tid >> 6;
    const float* xb = x + (size_t)b * CIN * HW + pixbase + p;

    #pragma unroll
    for (int i = 0; i < 32; ++i) {
        int k = kw * 32 + i;
        float v = xb[(size_t)k * HW];
        _Float16 h = (_Float16)v;
        _Float16 l = (_Float16)(v - (float)h);
        unsigned int pack = (unsigned int)h_bits(h) | ((unsigned int)h_bits(l) << 16);
        lds[(p * 128 + k) ^ (p & 31)] = pack;
    }
    __syncthreads();

    const int p2 = tid >> 2;
    const int qk = (tid & 3) * 32;
    const int s = (p2 & 7) << 3;
    unsigned int hw_[16], lw_[16];
    #pragma unroll
    for (int i = 0; i < 16; ++i) {
        int pos0 = qk + 2 * i;
        int src0 = pos0 ^ s;
        unsigned int a0 = lds[(p2 * 128 + src0) ^ (p2 & 31)];
        unsigned int a1 = lds[(p2 * 128 + src0 + 1) ^ (p2 & 31)];
        hw_[i] = (a0 & 0xffffu) | (a1 << 16);
        lw_[i] = (a0 >> 16) | (a1 & 0xffff0000u);
    }
    size_t orow = ((size_t)b * HW + pixbase + p2) * 64 + (qk >> 1);
    unsigned int* oh = (unsigned int*)xh_t;
    unsigned int* ol = (unsigned int*)xl_t;
    #pragma unroll
    for (int i = 0; i < 4; ++i) {
        uint4 th = {hw_[i*4], hw_[i*4+1], hw_[i*4+2], hw_[i*4+3]};
        uint4 tl = {lw_[i*4], lw_[i*4+1], lw_[i*4+2], lw_[i*4+3]};
        *(uint4*)&oh[orow + i * 4] = th;
        *(uint4*)&ol[orow + i * 4] = tl;
    }
}

// ---------------- Kernel 1: conv via f16-split MFMA (unchanged) ----------------
__global__ __launch_bounds__(256) void conv_mfma(
    const _Float16* __restrict__ xh_t, const _Float16* __restrict__ xl_t,
    const _Float16* __restrict__ wh_t, const _Float16* __restrict__ wl_t,
    float* __restrict__ qbuf, float* __restrict__ kbuf)
{
    __shared__ _Float16 xsh[128 * 64];
    __shared__ _Float16 xsl[128 * 64];
    __shared__ _Float16 wsh[128 * 64];
    __shared__ _Float16 wsl[128 * 64];

    const int tid = threadIdx.x;
    const int lane = tid & 63;
    const int wave = tid >> 6;
    const int pixbase = blockIdx.x * 128;
    const int b = blockIdx.y;
    const int half = blockIdx.z;
    const int wbase = half * 128;

    const int wrow = (wave & 1) * 64;
    const int wpix = (wave >> 1) * 64;

    f32x4 acc[4][4];
    #pragma unroll
    for (int m = 0; m < 4; ++m)
        #pragma unroll
        for (int n = 0; n < 4; ++n) { acc[m][n][0]=0.f; acc[m][n][1]=0.f; acc[m][n][2]=0.f; acc[m][n][3]=0.f; }

    const size_t xrow = ((size_t)b * HW + pixbase) * 128;

    #pragma unroll
    for (int kc = 0; kc < 2; ++kc) {
        if (kc) __syncthreads();
        #pragma unroll
        for (int i = 0; i < 4; ++i) {
            int sgl = wave * 4 + i;
            int pix = sgl * 8 + (lane >> 3);
            int j = lane & 7;
            const _Float16* gh = xh_t + xrow + (size_t)pix * 128 + kc * 64 + j * 8;
            const _Float16* gl = xl_t + xrow + (size_t)pix * 128 + kc * 64 + j * 8;
            gl_lds16(gh, (void*)(xsh + sgl * 512));
            gl_lds16(gl, (void*)(xsl + sgl * 512));
        }
        #pragma unroll
        for (int i = 0; i < 4; ++i) {
            int sgl = wave * 4 + i;
            int o = sgl * 8 + (lane >> 3);
            int j = lane & 7;
            const _Float16* gh = wh_t + (size_t)(wbase + o) * 128 + kc * 64 + j * 8;
            const _Float16* gl = wl_t + (size_t)(wbase + o) * 128 + kc * 64 + j * 8;
            gl_lds16(gh, (void*)(wsh + sgl * 512));
            gl_lds16(gl, (void*)(wsl + sgl * 512));
        }
        __syncthreads();

        #pragma unroll
        for (int ks = 0; ks < 2; ++ks) {
            const int kb = ks * 32 + (lane >> 4) * 8;
            half8 ah[4], al[4];
            #pragma unroll
            for (int m = 0; m < 4; ++m) {
                int o = wrow + m * 16 + (lane & 15);
                int idx = (o * 64 + kb) ^ ((o & 7) << 3);
                ah[m] = *(const half8*)&wsh[idx];
                al[m] = *(const half8*)&wsl[idx];
            }
            #pragma unroll
            for (int n = 0; n < 4; ++n) {
                int p = wpix + n * 16 + (lane & 15);
                int idx = (p * 64 + kb) ^ ((p & 7) << 3);
                half8 bh = *(const half8*)&xsh[idx];
                half8 bl = *(const half8*)&xsl[idx];
                #pragma unroll
                for (int m = 0; m < 4; ++m) {
                    mfma16(acc[m][n], ah[m], bh);
                    mfma16(acc[m][n], al[m], bh);
                    mfma16(acc[m][n], ah[m], bl);
                }
            }
        }
    }

    asm volatile("s_nop 7\n\ts_nop 7"
        : "+v"(acc[0][0]), "+v"(acc[0][1]), "+v"(acc[0][2]), "+v"(acc[0][3]),
          "+v"(acc[1][0]), "+v"(acc[1][1]), "+v"(acc[1][2]), "+v"(acc[1][3]),
          "+v"(acc[2][0]), "+v"(acc[2][1]), "+v"(acc[2][2]), "+v"(acc[2][3]),
          "+v"(acc[3][0]), "+v"(acc[3][1]), "+v"(acc[3][2]), "+v"(acc[3][3]));

    float* obuf = half ? kbuf : qbuf;
    #pragma unroll
    for (int m = 0; m < 4; ++m) {
        #pragma unroll
        for (int n = 0; n < 4; ++n) {
            int pc = pixbase + wpix + n * 16 + (lane & 15);
            #pragma unroll
            for (int r = 0; r < 4; ++r) {
                int row = wrow + m * 16 + (lane >> 4) * 4 + r;
                obuf[((size_t)b * COUT + row) * HW + pc] = acc[m][n][r];
            }
        }
    }
}

// ---------------- Kernel 2: attention v10 — packed-f32 row pairs ----------------
// Ablation (round 13): math issue = ~2/3 of attn time. This halves the VALU
// count: rows (dh,dh+1) processed as f32x2 pairs with explicit v_pk_fma/add;
// per 2 elems: 1 pk_fma(arg) + 2 exp + 1 pk_add(s) + 1 pk_fma(a).
// Pair loads {ks[o], ks[o+40]} merge to ds_read2_b32. Tail row dh=6 scalar.
__global__ __launch_bounds__(256) void attn_v10(
    const float* __restrict__ qbuf,
    const float* __restrict__ kbuf,
    const float* __restrict__ v,
    const float* __restrict__ rel_h,
    const float* __restrict__ rel_w,
    float* __restrict__ out)
{
    __shared__ __align__(16) float ks[38 * 40];
    __shared__ __align__(16) float vs[38 * 40];

    const int tid = threadIdx.x;
    const int tile = blockIdx.x;           // 0..8
    const int bc = blockIdx.y;             // 0..255
    const int c = bc & 127;
    const int tw = (tile % 3) * 32;
    const int th = (tile / 3) * 32;

    const float* kp = kbuf + (size_t)bc * HW;
    const float* vp = v    + (size_t)bc * HW;

    for (int idx = tid; idx < 38 * 38; idx += 256) {
        int r = idx / 38, cl = idx - r * 38;
        int gr = th - 3 + r, gc = tw - 3 + cl;
        bool ok = ((unsigned)gr < 96u) && ((unsigned)gc < 96u);
        ks[r * 40 + cl] = ok ? kp[gr * 96 + gc] : 0.f;
        vs[r * 40 + cl] = ok ? vp[gr * 96 + gc] : 0.f;
    }

    const bool is_h = (c < 64);
    const float* rbase = is_h ? (rel_h + c * 7) : (rel_w + (c - 64) * 7);
    float r7[7];
    #pragma unroll
    for (int i = 0; i < 7; ++i) r7[i] = rbase[i];

    const int ty = tid >> 3;   // 0..31
    const int tx = tid & 7;    // 0..7

    const float* qrow = qbuf + (size_t)bc * HW + (th + ty) * 96 + tw + tx * 4;
    float4 qa = *(const float4*)qrow;
    const float L2E = 1.4426950408889634f;
    float q2[4] = {qa.x * L2E, qa.y * L2E, qa.z * L2E, qa.w * L2E};
    f32x2 q2p[4];
    #pragma unroll
    for (int j = 0; j < 4; ++j) q2p[j] = (f32x2){q2[j], q2[j]};

    // rel pairs: is_h -> {r7[2rp], r7[2rp+1]} per row-pair; is_w -> {r7[dw],r7[dw]}
    f32x2 r7p[3];
    #pragma unroll
    for (int rp = 0; rp < 3; ++rp) r7p[rp] = (f32x2){r7[2*rp], r7[2*rp+1]};
    f32x2 rwp[7];
    #pragma unroll
    for (int dw = 0; dw < 7; ++dw) rwp[dw] = (f32x2){r7[dw], r7[dw]};

    f32x2 s2[4], a2[4];
    #pragma unroll
    for (int j = 0; j < 4; ++j) { s2[j] = (f32x2){0.f, 0.f}; a2[j] = (f32x2){0.f, 0.f}; }

    __syncthreads();

    const int base = ty * 40 + tx * 4;

    #pragma unroll
    for (int rp = 0; rp < 3; ++rp) {
        // paired loads: {row, row+1} -> ds_read2_b32 (offsets o, o+40 dwords)
        f32x2 kpr[10], vpr[10];
        #pragma unroll
        for (int i = 0; i < 10; ++i) {
            const float* pk_ = &ks[base + rp * 80 + i];
            const float* pv_ = &vs[base + rp * 80 + i];
            kpr[i] = (f32x2){pk_[0], pk_[40]};
            vpr[i] = (f32x2){pv_[0], pv_[40]};
        }

        if (is_h) {
            #pragma unroll
            for (int j = 0; j < 4; ++j) {
                f32x2 qr = pk_mul(q2p[j], r7p[rp]);
                #pragma unroll
                for (int dw = 0; dw < 7; ++dw) {
                    f32x2 arg = pk_fma(q2p[j], kpr[j + dw], qr);
                    f32x2 e = {fast_exp2(arg.x), fast_exp2(arg.y)};
                    s2[j] = pk_add(s2[j], e);
                    a2[j] = pk_fma(e, vpr[j + dw], a2[j]);
                }
            }
        } else {
            #pragma unroll
            for (int j = 0; j < 4; ++j) {
                #pragma unroll
                for (int dw = 0; dw < 7; ++dw) {
                    f32x2 t = pk_add(kpr[j + dw], rwp[dw]);
                    f32x2 arg = pk_mul(q2p[j], t);
                    f32x2 e = {fast_exp2(arg.x), fast_exp2(arg.y)};
                    s2[j] = pk_add(s2[j], e);
                    a2[j] = pk_fma(e, vpr[j + dw], a2[j]);
                }
            }
        }
    }

    // tail row dh = 6 (scalar into .x halves)
    {
        const float* kr0 = &ks[base + 6 * 40];
        const float* vr0 = &vs[base + 6 * 40];
        float kr[12], vr[12];
        #pragma unroll
        for (int t = 0; t < 3; ++t) {
            *(float4*)&kr[t * 4] = *(const float4*)&kr0[t * 4];
            *(float4*)&vr[t * 4] = *(const float4*)&vr0[t * 4];
        }
        if (is_h) {
            float rh = r7[6];
            #pragma unroll
            for (int j = 0; j < 4; ++j) {
                float qr = q2[j] * rh;
                #pragma unroll
                for (int dw = 0; dw < 7; ++dw) {
                    float e = fast_exp2(fmaf(q2[j], kr[j + dw], qr));
                    s2[j].x += e;
                    a2[j].x = fmaf(e, vr[j + dw], a2[j].x);
                }
            }
        } else {
            #pragma unroll
            for (int j = 0; j < 4; ++j) {
                #pragma unroll
                for (int dw = 0; dw < 7; ++dw) {
                    float e = fast_exp2(q2[j] * (kr[j + dw] + r7[dw]));
                    s2[j].x += e;
                    a2[j].x = fmaf(e, vr[j + dw], a2[j].x);
                }
            }
        }
    }

    float* orow = out + (size_t)bc * HW + (th + ty) * 96 + tw + tx * 4;
    float4 o4;
    o4.x = (a2[0].x + a2[0].y) * __builtin_amdgcn_rcpf(s2[0].x + s2[0].y);
    o4.y = (a2[1].x + a2[1].y) * __builtin_amdgcn_rcpf(s2[1].x + s2[1].y);
    o4.z = (a2[2].x + a2[2].y) * __builtin_amdgcn_rcpf(s2[2].x + s2[2].y);
    o4.w = (a2[3].x + a2[3].y) * __builtin_amdgcn_rcpf(s2[3].x + s2[3].y);
    *(float4*)orow = o4;
}

extern "C" void kernel_launch(void* const* d_in, const int* in_sizes, int n_in,
                              void* d_out, int out_size, void* d_ws, size_t ws_size,
                              hipStream_t stream) {
    const float* x  = (const float*)d_in[0];
    const float* v  = (const float*)d_in[1];
    const float* wq = (const float*)d_in[2];
    const float* wk = (const float*)d_in[3];
    const float* rh = (const float*)d_in[4];
    const float* rw = (const float*)d_in[5];
    float* out = (float*)d_out;

    float* qbuf = (float*)d_ws;
    float* kbuf = qbuf + (size_t)2 * COUT * HW;
    _Float16* xh = (_Float16*)(kbuf + (size_t)2 * COUT * HW);
    _Float16* xl = xh + (size_t)2 * HW * 128;
    _Float16* wh = xl + (size_t)2 * HW * 128;
    _Float16* wl = wh + 256 * 128;

    prep<<<dim3(152, 2), 256, 0, stream>>>(x, wq, wk, xh, xl, wh, wl);
    conv_mfma<<<dim3(72, 2, 2), 256, 0, stream>>>(xh, xl, wh, wl, qbuf, kbuf);
    attn_v10<<<dim3(9, 256), 256, 0, stream>>>(qbuf, kbuf, v, rh, rw, out);
}

// Round 15
// 48.335 us; speedup vs baseline: 7.9907x; 1.0191x over previous
//
#include <hip/hip_runtime.h>
#include <hip/hip_bf16.h>

#define HW 9216   // 96*96
#define CIN 128
#define COUT 128
#define NTILES 2304   // 9 tiles x 256 (b,c) planes
#define NBLK 1024     // persistent blocks

typedef _Float16 half8 __attribute__((ext_vector_type(8)));
typedef float f32x4 __attribute__((ext_vector_type(4)));

__device__ __forceinline__ float fast_exp2(float x) {
    float r;
    asm("v_exp_f32 %0, %1" : "=v"(r) : "v"(x));
    return r;
}

__device__ __forceinline__ void mfma16(f32x4& d, half8 a, half8 b) {
    asm("v_mfma_f32_16x16x32_f16 %0, %1, %2, %0" : "+v"(d) : "v"(a), "v"(b));
}

__device__ __forceinline__ void gl_lds16(const void* g, void* l) {
    __builtin_amdgcn_global_load_lds(
        (const __attribute__((address_space(1))) unsigned int*)g,
        (__attribute__((address_space(3))) unsigned int*)l, 16, 0, 0);
}

__device__ __forceinline__ unsigned short h_bits(_Float16 h) {
    return __builtin_bit_cast(unsigned short, h);
}

// ---------------- Kernel 0: prep (unchanged) ----------------
__global__ __launch_bounds__(256) void prep(
    const float* __restrict__ x,
    const float* __restrict__ wq, const float* __restrict__ wk,
    _Float16* __restrict__ xh_t, _Float16* __restrict__ xl_t,
    _Float16* __restrict__ wh_t, _Float16* __restrict__ wl_t)
{
    const int tid = threadIdx.x;
    const int bx = blockIdx.x;
    const int b = blockIdx.y;

    if (bx >= 144) {
        if (b) return;
        int o = (bx - 144) * 32 + (tid >> 3);
        int k0 = (tid & 7) * 16;
        const float* src = (o < 128) ? (wq + o * 128) : (wk + (o - 128) * 128);
        float vals[16];
        #pragma unroll
        for (int t = 0; t < 4; ++t)
            *(float4*)&vals[t * 4] = *(const float4*)&src[k0 + t * 4];
        half8 h0, h1, l0, l1;
        #pragma unroll
        for (int j = 0; j < 8; ++j) {
            _Float16 h = (_Float16)vals[j];
            h0[j] = h; l0[j] = (_Float16)(vals[j] - (float)h);
            _Float16 h2 = (_Float16)vals[j + 8];
            h1[j] = h2; l1[j] = (_Float16)(vals[j + 8] - (float)h2);
        }
        int s = (o & 7) << 3;
        *(half8*)&wh_t[o * 128 + (k0 ^ s)]       = h0;
        *(half8*)&wh_t[o * 128 + ((k0 + 8) ^ s)] = h1;
        *(half8*)&wl_t[o * 128 + (k0 ^ s)]       = l0;
        *(half8*)&wl_t[o * 128 + ((k0 + 8) ^ s)] = l1;
        return;
    }

    __shared__ unsigned int lds[64 * 128];
    const int pixbase = bx * 64;
    const int p = tid & 63;
    const int kw = tid >> 6;
    const float* xb = x + (size_t)b * CIN * HW + pixbase + p;

    #pragma unroll
    for (int i = 0; i < 32; ++i) {
        int k = kw * 32 + i;
        float v = xb[(size_t)k * HW];
        _Float16 h = (_Float16)v;
        _Float16 l = (_Float16)(v - (float)h);
        unsigned int pack = (unsigned int)h_bits(h) | ((unsigned int)h_bits(l) << 16);
        lds[(p * 128 + k) ^ (p & 31)] = pack;
    }
    __syncthreads();

    const int p2 = tid >> 2;
    const int qk = (tid & 3) * 32;
    const int s = (p2 & 7) << 3;
    unsigned int hw_[16], lw_[16];
    #pragma unroll
    for (int i = 0; i < 16; ++i) {
        int pos0 = qk + 2 * i;
        int src0 = pos0 ^ s;
        unsigned int a0 = lds[(p2 * 128 + src0) ^ (p2 & 31)];
        unsigned int a1 = lds[(p2 * 128 + src0 + 1) ^ (p2 & 31)];
        hw_[i] = (a0 & 0xffffu) | (a1 << 16);
        lw_[i] = (a0 >> 16) | (a1 & 0xffff0000u);
    }
    size_t orow = ((size_t)b * HW + pixbase + p2) * 64 + (qk >> 1);
    unsigned int* oh = (unsigned int*)xh_t;
    unsigned int* ol = (unsigned int*)xl_t;
    #pragma unroll
    for (int i = 0; i < 4; ++i) {
        uint4 th = {hw_[i*4], hw_[i*4+1], hw_[i*4+2], hw_[i*4+3]};
        uint4 tl = {lw_[i*4], lw_[i*4+1], lw_[i*4+2], lw_[i*4+3]};
        *(uint4*)&oh[orow + i * 4] = th;
        *(uint4*)&ol[orow + i * 4] = tl;
    }
}

// ---------------- Kernel 1: conv via f16-split MFMA (unchanged) ----------------
__global__ __launch_bounds__(256) void conv_mfma(
    const _Float16* __restrict__ xh_t, const _Float16* __restrict__ xl_t,
    const _Float16* __restrict__ wh_t, const _Float16* __restrict__ wl_t,
    float* __restrict__ qbuf, float* __restrict__ kbuf)
{
    __shared__ _Float16 xsh[128 * 64];
    __shared__ _Float16 xsl[128 * 64];
    __shared__ _Float16 wsh[128 * 64];
    __shared__ _Float16 wsl[128 * 64];

    const int tid = threadIdx.x;
    const int lane = tid & 63;
    const int wave = tid >> 6;
    const int pixbase = blockIdx.x * 128;
    const int b = blockIdx.y;
    const int half = blockIdx.z;
    const int wbase = half * 128;

    const int wrow = (wave & 1) * 64;
    const int wpix = (wave >> 1) * 64;

    f32x4 acc[4][4];
    #pragma unroll
    for (int m = 0; m < 4; ++m)
        #pragma unroll
        for (int n = 0; n < 4; ++n) { acc[m][n][0]=0.f; acc[m][n][1]=0.f; acc[m][n][2]=0.f; acc[m][n][3]=0.f; }

    const size_t xrow = ((size_t)b * HW + pixbase) * 128;

    #pragma unroll
    for (int kc = 0; kc < 2; ++kc) {
        if (kc) __syncthreads();
        #pragma unroll
        for (int i = 0; i < 4; ++i) {
            int sgl = wave * 4 + i;
            int pix = sgl * 8 + (lane >> 3);
            int j = lane & 7;
            const _Float16* gh = xh_t + xrow + (size_t)pix * 128 + kc * 64 + j * 8;
            const _Float16* gl = xl_t + xrow + (size_t)pix * 128 + kc * 64 + j * 8;
            gl_lds16(gh, (void*)(xsh + sgl * 512));
            gl_lds16(gl, (void*)(xsl + sgl * 512));
        }
        #pragma unroll
        for (int i = 0; i < 4; ++i) {
            int sgl = wave * 4 + i;
            int o = sgl * 8 + (lane >> 3);
            int j = lane & 7;
            const _Float16* gh = wh_t + (size_t)(wbase + o) * 128 + kc * 64 + j * 8;
            const _Float16* gl = wl_t + (size_t)(wbase + o) * 128 + kc * 64 + j * 8;
            gl_lds16(gh, (void*)(wsh + sgl * 512));
            gl_lds16(gl, (void*)(wsl + sgl * 512));
        }
        __syncthreads();

        #pragma unroll
        for (int ks = 0; ks < 2; ++ks) {
            const int kb = ks * 32 + (lane >> 4) * 8;
            half8 ah[4], al[4];
            #pragma unroll
            for (int m = 0; m < 4; ++m) {
                int o = wrow + m * 16 + (lane & 15);
                int idx = (o * 64 + kb) ^ ((o & 7) << 3);
                ah[m] = *(const half8*)&wsh[idx];
                al[m] = *(const half8*)&wsl[idx];
            }
            #pragma unroll
            for (int n = 0; n < 4; ++n) {
                int p = wpix + n * 16 + (lane & 15);
                int idx = (p * 64 + kb) ^ ((p & 7) << 3);
                half8 bh = *(const half8*)&xsh[idx];
                half8 bl = *(const half8*)&xsl[idx];
                #pragma unroll
                for (int m = 0; m < 4; ++m) {
                    mfma16(acc[m][n], ah[m], bh);
                    mfma16(acc[m][n], al[m], bh);
                    mfma16(acc[m][n], ah[m], bl);
                }
            }
        }
    }

    asm volatile("s_nop 7\n\ts_nop 7"
        : "+v"(acc[0][0]), "+v"(acc[0][1]), "+v"(acc[0][2]), "+v"(acc[0][3]),
          "+v"(acc[1][0]), "+v"(acc[1][1]), "+v"(acc[1][2]), "+v"(acc[1][3]),
          "+v"(acc[2][0]), "+v"(acc[2][1]), "+v"(acc[2][2]), "+v"(acc[2][3]),
          "+v"(acc[3][0]), "+v"(acc[3][1]), "+v"(acc[3][2]), "+v"(acc[3][3]));

    float* obuf = half ? kbuf : qbuf;
    #pragma unroll
    for (int m = 0; m < 4; ++m) {
        #pragma unroll
        for (int n = 0; n < 4; ++n) {
            int pc = pixbase + wpix + n * 16 + (lane & 15);
            #pragma unroll
            for (int r = 0; r < 4; ++r) {
                int row = wrow + m * 16 + (lane >> 4) * 4 + r;
                obuf[((size_t)b * COUT + row) * HW + pc] = acc[m][n][r];
            }
        }
    }
}

// ---------------- Kernel 2: attn v11 — persistent + double-buffered ----------------
// 1024 persistent blocks grid-stride 2304 tiles. Per iteration: write staged
// regs -> LDS[cur]; ONE barrier; issue next tile's global loads (latency hides
// under math); run v8 math on LDS[cur]; swap buffers. Attacks the measured
// stall component (warm rep 27us vs ~11us issue): stage/math serialization.
__global__ __launch_bounds__(256) void attn_v11(
    const float* __restrict__ qbuf,
    const float* __restrict__ kbuf,
    const float* __restrict__ v,
    const float* __restrict__ rel_h,
    const float* __restrict__ rel_w,
    float* __restrict__ out)
{
    __shared__ __align__(16) float ks[2][38 * 40];
    __shared__ __align__(16) float vs[2][38 * 40];

    const int tid = threadIdx.x;
    const int ty = tid >> 3;   // 0..31 (row)
    const int tx = tid & 7;    // 0..7  (col group of 4)
    const float L2E = 1.4426950408889634f;

    float kstg[6], vstg[6];
    float4 qstg;

    int t = blockIdx.x;

    // ---- phase A: stage first tile into registers ----
    {
        int bc = t / 9, tl = t - bc * 9;
        int th = (tl / 3) * 32, tw = (tl % 3) * 32;
        const float* kp = kbuf + (size_t)bc * HW;
        const float* vp = v    + (size_t)bc * HW;
        #pragma unroll
        for (int i = 0; i < 6; ++i) {
            int idx = tid + i * 256;
            int r = idx / 38, cl = idx - r * 38;
            int gr = th - 3 + r, gc = tw - 3 + cl;
            bool ok = (idx < 1444) && ((unsigned)gr < 96u) && ((unsigned)gc < 96u);
            kstg[i] = ok ? kp[gr * 96 + gc] : 0.f;
            vstg[i] = ok ? vp[gr * 96 + gc] : 0.f;
        }
        qstg = *(const float4*)(qbuf + (size_t)bc * HW + (th + ty) * 96 + tw + tx * 4);
    }

    int cur = 0;
    for (;;) {
        // ---- current tile params ----
        const int bc = t / 9, tl = t - bc * 9;
        const int th = (tl / 3) * 32, tw = (tl % 3) * 32;
        const int c = bc & 127;
        const bool is_h = (c < 64);
        const float* rbase = is_h ? (rel_h + c * 7) : (rel_w + (c - 64) * 7);
        float r7[7];
        #pragma unroll
        for (int i = 0; i < 7; ++i) r7[i] = rbase[i];
        float q2[4] = {qstg.x * L2E, qstg.y * L2E, qstg.z * L2E, qstg.w * L2E};

        // ---- write staged regs -> LDS[cur] ----
        #pragma unroll
        for (int i = 0; i < 6; ++i) {
            int idx = tid + i * 256;
            if (idx < 1444) {
                int r = idx / 38, cl = idx - r * 38;
                ks[cur][r * 40 + cl] = kstg[i];
                vs[cur][r * 40 + cl] = vstg[i];
            }
        }
        __syncthreads();   // single barrier per iteration

        // ---- phase A for NEXT tile: issue loads, latency hides under math ----
        const int tn = t + NBLK;
        const bool more = (tn < NTILES);
        if (more) {
            int bc2 = tn / 9, tl2 = tn - bc2 * 9;
            int th2 = (tl2 / 3) * 32, tw2 = (tl2 % 3) * 32;
            const float* kp = kbuf + (size_t)bc2 * HW;
            const float* vp = v    + (size_t)bc2 * HW;
            #pragma unroll
            for (int i = 0; i < 6; ++i) {
                int idx = tid + i * 256;
                int r = idx / 38, cl = idx - r * 38;
                int gr = th2 - 3 + r, gc = tw2 - 3 + cl;
                bool ok = (idx < 1444) && ((unsigned)gr < 96u) && ((unsigned)gc < 96u);
                kstg[i] = ok ? kp[gr * 96 + gc] : 0.f;
                vstg[i] = ok ? vp[gr * 96 + gc] : 0.f;
            }
            qstg = *(const float4*)(qbuf + (size_t)bc2 * HW + (th2 + ty) * 96 + tw2 + tx * 4);
        }

        // ---- math on LDS[cur] (v8 body) ----
        float s[4] = {0.f, 0.f, 0.f, 0.f};
        float a[4] = {0.f, 0.f, 0.f, 0.f};
        const float* kb0 = &ks[cur][ty * 40 + tx * 4];
        const float* vb0 = &vs[cur][ty * 40 + tx * 4];

        #pragma unroll
        for (int dh = 0; dh < 7; ++dh) {
            float kr[12], vr[12];
            #pragma unroll
            for (int tt = 0; tt < 3; ++tt) {
                *(float4*)&kr[tt * 4] = *(const float4*)&kb0[dh * 40 + tt * 4];
                *(float4*)&vr[tt * 4] = *(const float4*)&vb0[dh * 40 + tt * 4];
            }

            if (is_h) {
                float rh = r7[dh];
                #pragma unroll
                for (int j = 0; j < 4; ++j) {
                    float qr = q2[j] * rh;
                    #pragma unroll
                    for (int dw = 0; dw < 7; ++dw) {
                        float e = fast_exp2(fmaf(q2[j], kr[j + dw], qr));
                        s[j] += e;
                        a[j] = fmaf(e, vr[j + dw], a[j]);
                    }
                }
            } else {
                #pragma unroll
                for (int j = 0; j < 4; ++j) {
                    #pragma unroll
                    for (int dw = 0; dw < 7; ++dw) {
                        float e = fast_exp2(q2[j] * (kr[j + dw] + r7[dw]));
                        s[j] += e;
                        a[j] = fmaf(e, vr[j + dw], a[j]);
                    }
                }
            }
        }

        float* orow = out + (size_t)bc * HW + (th + ty) * 96 + tw + tx * 4;
        float4 o4;
        o4.x = a[0] * __builtin_amdgcn_rcpf(s[0]);
        o4.y = a[1] * __builtin_amdgcn_rcpf(s[1]);
        o4.z = a[2] * __builtin_amdgcn_rcpf(s[2]);
        o4.w = a[3] * __builtin_amdgcn_rcpf(s[3]);
        *(float4*)orow = o4;

        if (!more) break;
        t = tn;
        cur ^= 1;
    }
}

extern "C" void kernel_launch(void* const* d_in, const int* in_sizes, int n_in,
                              void* d_out, int out_size, void* d_ws, size_t ws_size,
                              hipStream_t stream) {
    const float* x  = (const float*)d_in[0];
    const float* v  = (const float*)d_in[1];
    const float* wq = (const float*)d_in[2];
    const float* wk = (const float*)d_in[3];
    const float* rh = (const float*)d_in[4];
    const float* rw = (const float*)d_in[5];
    float* out = (float*)d_out;

    float* qbuf = (float*)d_ws;
    float* kbuf = qbuf + (size_t)2 * COUT * HW;
    _Float16* xh = (_Float16*)(kbuf + (size_t)2 * COUT * HW);
    _Float16* xl = xh + (size_t)2 * HW * 128;
    _Float16* wh = xl + (size_t)2 * HW * 128;
    _Float16* wl = wh + 256 * 128;

    prep<<<dim3(152, 2), 256, 0, stream>>>(x, wq, wk, xh, xl, wh, wl);
    conv_mfma<<<dim3(72, 2, 2), 256, 0, stream>>>(xh, xl, wh, wl, qbuf, kbuf);
    attn_v11<<<dim3(NBLK), 256, 0, stream>>>(qbuf, kbuf, v, rh, rw, out);
}